// Round 11
// baseline (518.575 us; speedup 1.0000x reference)
//
#include <hip/hip_runtime.h>

// PointPillarScatter: scatter (B*P, C) pillar features into dense BEV canvas
// out[b][ch][y][x], zero elsewhere. B=8, C=64, NX=432, NY=496, NZ=1.
//
// Strategy: inverse map (pixel -> pillar) in d_ws, then ONE output-linear
// pass writes the 438.8 MB canvas exactly once, chip-wide contiguous
// (fill-kernel store pattern, 6.15 TB/s proven). Round-5 post-mortem:
// 1 store/thread behind 1 dependent map load ran at ~2.9 TB/s
// (latency/overhead-bound). v6: 4 float4 stores per thread with the 4 map
// loads issued as a 4-deep MLP batch; block count /4, overhead /4.
// Plain stores only: round 4 proved nontemporal stores drop write BW to
// 1.8 TB/s on gfx950 (bypasses L2 write-combining).

#define PPS_NX   432
#define PPS_NY   496
#define PPS_GRID (PPS_NX * PPS_NY)   // 214272, divisible by 16
#define PPS_C    64
#define PPS_B    8
#define PPS_U    (PPS_GRID / 4)      // 53568 float4-units per plane (div by 4)

typedef float f32x4 __attribute__((ext_vector_type(4)));

// ---- Kernel 1: init inverse map to -1 (6.86 MB) -------------------------
__global__ void pps_init_map(int4* __restrict__ map4, int n4) {
    int i = blockIdx.x * blockDim.x + threadIdx.x;
    if (i < n4) map4[i] = make_int4(-1, -1, -1, -1);
}

// ---- Kernel 2: scatter pillar indices into the map (32768 x 4 B) --------
__global__ void pps_scatter_idx(const int4* __restrict__ coords,
                                int* __restrict__ map, int P) {
    int p = blockIdx.x * blockDim.x + threadIdx.x;
    if (p >= P) return;
    int4 c = coords[p];   // (batch, z, y, x)
    int pos = c.y + c.z * PPS_NX + c.w;           // in-plane index
    map[c.x * PPS_GRID + pos] = p;
}

// ---- Kernel 3: output-linear canvas write, 4 float4 per thread ----------
// Thread t covers float4 indices q..q+3 of the canvas (64 B). PPS_U % 4 == 0
// so all 4 lie in one channel plane -> one plane/b/ch computation.
// The 4 map int4 loads are independent (issued together -> 1 latency
// exposure); ~93% of 4-pixel groups are empty -> pure zero store.
__global__ __launch_bounds__(256) void pps_write4(const float* __restrict__ pf,
                                                  const int* __restrict__ map,
                                                  f32x4* __restrict__ out4) {
    int t = blockIdx.x * 256 + threadIdx.x;       // 0 .. 6,856,703
    int q = t * 4;                                 // first float4 index
    int plane = (unsigned)q / PPS_U;               // magic-mul division
    int u = q - plane * PPS_U;
    int b = plane >> 6;
    int ch = plane & 63;

    const int4* mp = (const int4*)(map + (size_t)b * PPS_GRID) + u;
    int4 m0 = mp[0];
    int4 m1 = mp[1];
    int4 m2 = mp[2];
    int4 m3 = mp[3];

    const f32x4 z4 = {0.f, 0.f, 0.f, 0.f};
    f32x4 v0 = z4, v1 = z4, v2 = z4, v3 = z4;
    const float* pfc = pf + ch;

    // empty entry == -1 (sign bit); AND >= 0 iff any of the 4 pixels occupied
    if ((m0.x & m0.y & m0.z & m0.w) >= 0) {
        if (m0.x >= 0) v0.x = pfc[(size_t)m0.x * PPS_C];
        if (m0.y >= 0) v0.y = pfc[(size_t)m0.y * PPS_C];
        if (m0.z >= 0) v0.z = pfc[(size_t)m0.z * PPS_C];
        if (m0.w >= 0) v0.w = pfc[(size_t)m0.w * PPS_C];
    }
    if ((m1.x & m1.y & m1.z & m1.w) >= 0) {
        if (m1.x >= 0) v1.x = pfc[(size_t)m1.x * PPS_C];
        if (m1.y >= 0) v1.y = pfc[(size_t)m1.y * PPS_C];
        if (m1.z >= 0) v1.z = pfc[(size_t)m1.z * PPS_C];
        if (m1.w >= 0) v1.w = pfc[(size_t)m1.w * PPS_C];
    }
    if ((m2.x & m2.y & m2.z & m2.w) >= 0) {
        if (m2.x >= 0) v2.x = pfc[(size_t)m2.x * PPS_C];
        if (m2.y >= 0) v2.y = pfc[(size_t)m2.y * PPS_C];
        if (m2.z >= 0) v2.z = pfc[(size_t)m2.z * PPS_C];
        if (m2.w >= 0) v2.w = pfc[(size_t)m2.w * PPS_C];
    }
    if ((m3.x & m3.y & m3.z & m3.w) >= 0) {
        if (m3.x >= 0) v3.x = pfc[(size_t)m3.x * PPS_C];
        if (m3.y >= 0) v3.y = pfc[(size_t)m3.y * PPS_C];
        if (m3.z >= 0) v3.z = pfc[(size_t)m3.z * PPS_C];
        if (m3.w >= 0) v3.w = pfc[(size_t)m3.w * PPS_C];
    }

    f32x4* o = out4 + q;
    o[0] = v0;   // plain stores: keep L2 write-combining
    o[1] = v1;
    o[2] = v2;
    o[3] = v3;
}

// ---- Fallback (ws too small): zero + direct scatter ---------------------
__global__ void pps_zero_out(float4* __restrict__ out, long long n4) {
    long long i = (long long)blockIdx.x * blockDim.x + threadIdx.x;
    const long long stride = (long long)gridDim.x * blockDim.x;
    const float4 z = make_float4(0.f, 0.f, 0.f, 0.f);
    for (; i < n4; i += stride) out[i] = z;
}
__global__ void pps_scatter_feat(const float* __restrict__ pf,
                                 const int4* __restrict__ coords,
                                 float* __restrict__ out, int P) {
    int t = blockIdx.x * blockDim.x + threadIdx.x;
    int p = t >> 6;
    if (p >= P) return;
    int ch = t & 63;
    int4 c = coords[p];
    long long pos = (long long)c.x * (long long)(PPS_C * PPS_GRID)
                  + (long long)ch * PPS_GRID
                  + (long long)(c.y + c.z * PPS_NX + c.w);
    out[pos] = pf[t];
}

extern "C" void kernel_launch(void* const* d_in, const int* in_sizes, int n_in,
                              void* d_out, int out_size, void* d_ws, size_t ws_size,
                              hipStream_t stream) {
    const float* pf     = (const float*)d_in[0];
    const int4*  coords = (const int4*)d_in[1];
    float*       out    = (float*)d_out;
    int P = in_sizes[0] / PPS_C;   // B * P_PER = 32768

    const size_t map_bytes = (size_t)PPS_B * PPS_GRID * sizeof(int);
    if (ws_size >= map_bytes) {
        int* map = (int*)d_ws;
        int n4 = PPS_B * PPS_U;                       // 428544 int4 entries
        pps_init_map<<<(n4 + 255) / 256, 256, 0, stream>>>((int4*)map, n4);
        pps_scatter_idx<<<(P + 255) / 256, 256, 0, stream>>>(coords, map, P);
        int total4 = out_size / 4;                    // 27,426,816
        int nthreads = total4 / 4;                    // 6,856,704
        pps_write4<<<nthreads / 256, 256, 0, stream>>>(pf, map, (f32x4*)out);
    } else {
        long long n4 = (long long)out_size / 4;
        pps_zero_out<<<2048, 256, 0, stream>>>((float4*)out, n4);
        int threads = P * PPS_C;
        pps_scatter_feat<<<(threads + 255) / 256, 256, 0, stream>>>(pf, coords, out, P);
    }
}

// Round 12
// 476.830 us; speedup vs baseline: 1.0875x; 1.0875x over previous
//
#include <hip/hip_runtime.h>

// PointPillarScatter: scatter (B*P, C) pillar features into dense BEV canvas
// out[b][ch][y][x], zero elsewhere. B=8, C=64, NX=432, NY=496, NZ=1.
//
// v7: block-chunked persistent write kernel.
// Evidence ladder: r4 nontemporal = 1.8 TB/s (partial-line writes);
// r5 one-contiguous-float4/thread = 2.9 TB/s (dispatch + latency bound);
// r11 4-consecutive-float4/thread = 1.9 TB/s (REGRESSION: per-instruction
// stores were 64B-strided partial lines); rocclr fill = 6.2 TB/s (many
// contiguous stores per thread, grid-stride).
// => every store instruction must be wave-contiguous AND each thread must
// do many of them. Here: each block streams a contiguous 128 KB chunk
// (8192 float4), 8 iters x {4 batched map loads -> 4 contiguous 4 KB
// block-stores}. 3348 x 8192 = 27,426,816 = total4 exactly (no tail).

#define PPS_NX   432
#define PPS_NY   496
#define PPS_GRID (PPS_NX * PPS_NY)   // 214272
#define PPS_C    64
#define PPS_B    8
#define PPS_U    (PPS_GRID / 4)      // 53568 float4-units per plane

typedef float f32x4 __attribute__((ext_vector_type(4)));

// ---- Kernel 1: init inverse map to -1 (6.86 MB) -------------------------
__global__ void pps_init_map(int4* __restrict__ map4, int n4) {
    int i = blockIdx.x * blockDim.x + threadIdx.x;
    if (i < n4) map4[i] = make_int4(-1, -1, -1, -1);
}

// ---- Kernel 2: scatter pillar indices into the map (32768 x 4 B) --------
__global__ void pps_scatter_idx(const int4* __restrict__ coords,
                                int* __restrict__ map, int P) {
    int p = blockIdx.x * blockDim.x + threadIdx.x;
    if (p >= P) return;
    int4 c = coords[p];   // (batch, z, y, x)
    int pos = c.y + c.z * PPS_NX + c.w;           // in-plane index
    map[c.x * PPS_GRID + pos] = p;
}

// ---- Kernel 3: block-chunked canvas write -------------------------------
// Block owns float4 indices [blockIdx*8192, +8192) -- 128 KB contiguous.
// Each iter: 4 batched independent map loads (one latency exposure), then
// 4 stores; each store instruction covers 256 threads x 16 B = 4 KB
// contiguous. ~93% of map int4s are all-empty -> pure zero store.
__global__ __launch_bounds__(256) void pps_write_gs(const float* __restrict__ pf,
                                                    const int* __restrict__ map,
                                                    f32x4* __restrict__ out4) {
    const int base = blockIdx.x * 8192 + threadIdx.x;

    #pragma unroll
    for (int k = 0; k < 8; ++k) {
        const int f0 = base + k * 1024;
        int4 mm[4];
        int  chs[4];
        #pragma unroll
        for (int j = 0; j < 4; ++j) {
            int f = f0 + j * 256;
            int plane = (unsigned)f / PPS_U;          // magic-mul division
            int u = f - plane * PPS_U;
            int b = plane >> 6;
            chs[j] = plane & 63;
            mm[j] = ((const int4*)(map + (size_t)b * PPS_GRID))[u];
        }
        #pragma unroll
        for (int j = 0; j < 4; ++j) {
            f32x4 v = {0.f, 0.f, 0.f, 0.f};
            const int4 m = mm[j];
            // empty entry == -1 (sign bit); AND >= 0 iff any pixel occupied
            if ((m.x & m.y & m.z & m.w) >= 0) {
                const float* pfc = pf + chs[j];
                if (m.x >= 0) v.x = pfc[(size_t)m.x * PPS_C];
                if (m.y >= 0) v.y = pfc[(size_t)m.y * PPS_C];
                if (m.z >= 0) v.z = pfc[(size_t)m.z * PPS_C];
                if (m.w >= 0) v.w = pfc[(size_t)m.w * PPS_C];
            }
            out4[f0 + j * 256] = v;   // plain store: keep L2 write-combining
        }
    }
}

// ---- Fallback (ws too small): zero + direct scatter ---------------------
__global__ void pps_zero_out(float4* __restrict__ out, long long n4) {
    long long i = (long long)blockIdx.x * blockDim.x + threadIdx.x;
    const long long stride = (long long)gridDim.x * blockDim.x;
    const float4 z = make_float4(0.f, 0.f, 0.f, 0.f);
    for (; i < n4; i += stride) out[i] = z;
}
__global__ void pps_scatter_feat(const float* __restrict__ pf,
                                 const int4* __restrict__ coords,
                                 float* __restrict__ out, int P) {
    int t = blockIdx.x * blockDim.x + threadIdx.x;
    int p = t >> 6;
    if (p >= P) return;
    int ch = t & 63;
    int4 c = coords[p];
    long long pos = (long long)c.x * (long long)(PPS_C * PPS_GRID)
                  + (long long)ch * PPS_GRID
                  + (long long)(c.y + c.z * PPS_NX + c.w);
    out[pos] = pf[t];
}

extern "C" void kernel_launch(void* const* d_in, const int* in_sizes, int n_in,
                              void* d_out, int out_size, void* d_ws, size_t ws_size,
                              hipStream_t stream) {
    const float* pf     = (const float*)d_in[0];
    const int4*  coords = (const int4*)d_in[1];
    float*       out    = (float*)d_out;
    int P = in_sizes[0] / PPS_C;   // B * P_PER = 32768

    const size_t map_bytes = (size_t)PPS_B * PPS_GRID * sizeof(int);
    if (ws_size >= map_bytes) {
        int* map = (int*)d_ws;
        int n4 = PPS_B * (PPS_GRID / 4);              // 428544 int4 entries
        pps_init_map<<<(n4 + 255) / 256, 256, 0, stream>>>((int4*)map, n4);
        pps_scatter_idx<<<(P + 255) / 256, 256, 0, stream>>>(coords, map, P);
        int total4 = out_size / 4;                    // 27,426,816
        int blocks = total4 / 8192;                   // 3348, exact
        pps_write_gs<<<blocks, 256, 0, stream>>>(pf, map, (f32x4*)out);
    } else {
        long long n4 = (long long)out_size / 4;
        pps_zero_out<<<2048, 256, 0, stream>>>((float4*)out, n4);
        int threads = P * PPS_C;
        pps_scatter_feat<<<(threads + 255) / 256, 256, 0, stream>>>(pf, coords, out, P);
    }
}